// Round 21
// baseline (1588.812 us; speedup 1.0000x reference)
//
#include <hip/hip_runtime.h>
#include <math.h>

#define NTOK 2048
#define DM 768
#define NHD 12
#define HS 64
#define SEQ 1024
#define HID 3072
#define NL 12

typedef __attribute__((ext_vector_type(8))) short short8;
typedef __attribute__((ext_vector_type(8))) unsigned short us8;
typedef __attribute__((ext_vector_type(4))) float f32x4;
typedef __attribute__((ext_vector_type(4))) unsigned short us4;
typedef unsigned short u16;

static __device__ __forceinline__ u16 f2bf(float f) {
    unsigned u = __float_as_uint(f);
    u = (u + 0x7fffu + ((u >> 16) & 1u)) >> 16;
    return (u16)u;
}
static __device__ __forceinline__ float bf2f(u16 v) {
    return __uint_as_float(((unsigned)v) << 16);
}

static __device__ __forceinline__ void gload16(const void* g, void* l) {
    __builtin_amdgcn_global_load_lds(
        (const __attribute__((address_space(1))) void*)g,
        (__attribute__((address_space(3))) void*)l,
        16, 0, 0);
}

// ---------------- fused x + sincos pos embed + LN1(layer0): 1 wave per row -----
__global__ __launch_bounds__(256) void posln_k(
        const float* __restrict__ xin, float* __restrict__ xbuf,
        const float* __restrict__ w, const float* __restrict__ b,
        u16* __restrict__ hbuf) {
    int l = threadIdx.x & 63, wv = threadIdx.x >> 6;
    int row = blockIdx.x * 4 + wv;
    int tok = row & (SEQ - 1);
    size_t ro = (size_t)row * DM;
    float4 v[3];
#pragma unroll
    for (int c = 0; c < 3; c++) {
        int col = c * 256 + l * 4;
        float4 x4 = *(const float4*)(xin + ro + col);
        float pe[4];
#pragma unroll
        for (int j = 0; j < 4; j++) {
            int d = col + j;
            int i = (d < 384) ? d : d - 384;
            float omega = expf((float)i * (-9.210340371976184f / 384.0f));
            float ang = (float)tok * omega;
            pe[j] = (d < 384) ? sinf(ang) : cosf(ang);
        }
        x4.x += pe[0]; x4.y += pe[1]; x4.z += pe[2]; x4.w += pe[3];
        *(float4*)(xbuf + ro + col) = x4;
        v[c] = x4;
    }
    float s = 0.f;
#pragma unroll
    for (int c = 0; c < 3; c++) s += v[c].x + v[c].y + v[c].z + v[c].w;
#pragma unroll
    for (int off = 32; off; off >>= 1) s += __shfl_xor(s, off, 64);
    float mu = s * (1.0f / DM);
    float vs = 0.f;
#pragma unroll
    for (int c = 0; c < 3; c++) {
        float dx;
        dx = v[c].x - mu; vs += dx * dx;
        dx = v[c].y - mu; vs += dx * dx;
        dx = v[c].z - mu; vs += dx * dx;
        dx = v[c].w - mu; vs += dx * dx;
    }
#pragma unroll
    for (int off = 32; off; off >>= 1) vs += __shfl_xor(vs, off, 64);
    float rstd = rsqrtf(vs * (1.0f / DM) + 1e-5f);
#pragma unroll
    for (int c = 0; c < 3; c++) {
        int col = c * 256 + l * 4;
        float4 w4 = *(const float4*)(w + col);
        float4 b4 = *(const float4*)(b + col);
        us4 u = { f2bf((v[c].x - mu) * rstd * w4.x + b4.x),
                  f2bf((v[c].y - mu) * rstd * w4.y + b4.y),
                  f2bf((v[c].z - mu) * rstd * w4.z + b4.z),
                  f2bf((v[c].w - mu) * rstd * w4.w + b4.w) };
        *(us4*)(hbuf + ro + col) = u;
    }
}

// ---------------- fp32 -> bf16, 4 tensors, NT 16B stores ----------------
// Writes bypass L3 (nontemporal) so the fp32 inputs stay L3-resident;
// bf16 outputs are small per-layer (14 MB) and L2-served for the GEMMs.
__global__ __launch_bounds__(256) void cvt4_k(
        const float* __restrict__ s0, u16* __restrict__ d0, unsigned nb0,
        const float* __restrict__ s1, u16* __restrict__ d1, unsigned nb1,
        const float* __restrict__ s2, u16* __restrict__ d2, unsigned nb2,
        const float* __restrict__ s3, u16* __restrict__ d3) {
    unsigned bb = blockIdx.x;
    const float* s; u16* d;
    if (bb < nb0) { s = s0; d = d0; }
    else { bb -= nb0;
        if (bb < nb1) { s = s1; d = d1; }
        else { bb -= nb1;
            if (bb < nb2) { s = s2; d = d2; }
            else { bb -= nb2; s = s3; d = d3; }
        }
    }
    unsigned base4 = bb * 512 + threadIdx.x * 2;
    float4 f0 = ((const float4*)s)[base4];
    float4 f1 = ((const float4*)s)[base4 + 1];
    us8 u;
    u[0] = f2bf(f0.x); u[1] = f2bf(f0.y); u[2] = f2bf(f0.z); u[3] = f2bf(f0.w);
    u[4] = f2bf(f1.x); u[5] = f2bf(f1.y); u[6] = f2bf(f1.z); u[7] = f2bf(f1.w);
    __builtin_nontemporal_store(u, (us8*)d + bb * 256 + threadIdx.x);
}

// ---------------- fp32 -> bf16 (x4), single tensor (fallback path) -------------
__global__ void cvt_k(const float* __restrict__ in, u16* __restrict__ out) {
    int idx = blockIdx.x * 256 + threadIdx.x;
    float4 f = ((const float4*)in)[idx];
    us4 u = { f2bf(f.x), f2bf(f.y), f2bf(f.z), f2bf(f.w) };
    ((us4*)out)[idx] = u;
}

// ---- fused split-K reduce + residual + LayerNorm: 1 wave per row --------------
// Partials are bf16; accumulate fp32 in fixed order (deterministic).
template<int SK, bool OUTBF>
__global__ __launch_bounds__(256) void skredln_k(
        const u16* __restrict__ cp, const float* __restrict__ bias,
        float* __restrict__ xres, const float* __restrict__ w,
        const float* __restrict__ b, void* __restrict__ out) {
    int l = threadIdx.x & 63, wv = threadIdx.x >> 6;
    int row = blockIdx.x * 4 + wv;
    size_t ro = (size_t)row * DM;
    float4 v[3];
#pragma unroll
    for (int c = 0; c < 3; c++) {
        int col = c * 256 + l * 4;
        float4 s = *(const float4*)(bias + col);
#pragma unroll
        for (int p = 0; p < SK; p++) {
            us4 pv = *(const us4*)(cp + (size_t)p * (NTOK * DM) + ro + col);
            s.x += bf2f(pv[0]); s.y += bf2f(pv[1]);
            s.z += bf2f(pv[2]); s.w += bf2f(pv[3]);
        }
        float4 x4 = *(const float4*)(xres + ro + col);
        x4.x += s.x; x4.y += s.y; x4.z += s.z; x4.w += s.w;
        *(float4*)(xres + ro + col) = x4;
        v[c] = x4;
    }
    float s = 0.f;
#pragma unroll
    for (int c = 0; c < 3; c++) s += v[c].x + v[c].y + v[c].z + v[c].w;
#pragma unroll
    for (int off = 32; off; off >>= 1) s += __shfl_xor(s, off, 64);
    float mu = s * (1.0f / DM);
    float vs = 0.f;
#pragma unroll
    for (int c = 0; c < 3; c++) {
        float dx;
        dx = v[c].x - mu; vs += dx * dx;
        dx = v[c].y - mu; vs += dx * dx;
        dx = v[c].z - mu; vs += dx * dx;
        dx = v[c].w - mu; vs += dx * dx;
    }
#pragma unroll
    for (int off = 32; off; off >>= 1) vs += __shfl_xor(vs, off, 64);
    float rstd = rsqrtf(vs * (1.0f / DM) + 1e-5f);
#pragma unroll
    for (int c = 0; c < 3; c++) {
        int col = c * 256 + l * 4;
        float4 w4 = *(const float4*)(w + col);
        float4 b4 = *(const float4*)(b + col);
        float y0 = (v[c].x - mu) * rstd * w4.x + b4.x;
        float y1 = (v[c].y - mu) * rstd * w4.y + b4.y;
        float y2 = (v[c].z - mu) * rstd * w4.z + b4.z;
        float y3 = (v[c].w - mu) * rstd * w4.w + b4.w;
        if (OUTBF) {
            us4 u = { f2bf(y0), f2bf(y1), f2bf(y2), f2bf(y3) };
            *(us4*)((u16*)out + ro + col) = u;
        } else {
            float4 o4 = { y0, y1, y2, y3 };
            *(float4*)((float*)out + ro + col) = o4;
        }
    }
}

// ---------------- LDS-staged GEMM, double-buffered, XCD-swizzled ---------------
// MODE 0: qkv scatter  1: residual add  2: GELU (ld HID)  3: split-K bf16 partial
template<int BM, int BN, int NT, int WR, int WC, int MODE>
__global__ __launch_bounds__(NT) void gemm_k(
        const u16* __restrict__ A, const u16* __restrict__ B,
        const float* __restrict__ bias, int K, int Kld,
        float* __restrict__ xres, u16* __restrict__ o0, u16* __restrict__ o1,
        u16* __restrict__ o2, u16* __restrict__ cp) {
    constexpr int WM = BM / WR, WN = BN / WC;
    constexpr int FM = WM / 16, FN = WN / 16;
    constexpr int ACH = (BM * 128) / (NT * 16);
    constexpr int BCH = (BN * 128) / (NT * 16);

    __shared__ u16 lA[2][BM * 64];
    __shared__ u16 lB[2][BN * 64];

    int tid = threadIdx.x;
    int l = tid & 63, w = tid >> 6;
    int lr = l & 15, lg = l >> 4;
    int wr = w / WC, wc = w % WC;

    int gx = gridDim.x, gy = gridDim.y;
    int nwg = gx * gy;
    int flat = blockIdx.y * gx + blockIdx.x;
    int virt = (flat & 7) * (nwg >> 3) + (flat >> 3);
    int bx = virt / gy;
    int by = virt % gy;
    int bm = by * BM;
    int bn = bx * BN;

    int koff = (MODE == 3) ? blockIdx.z * K : 0;
    const char* Ab = (const char*)A + (size_t)koff * 2;
    const char* Bb = (const char*)B + (size_t)koff * 2;
    u16* cpb = (MODE == 3) ? cp + (size_t)blockIdx.z * NTOK * DM : nullptr;

    auto stage = [&](int buf, int kk) {
#pragma unroll
        for (int c = 0; c < ACH; c++) {
            int p = (c * NT + tid) * 16;
            int row = p >> 7, kb = p & 127;
            int kbs = kb ^ ((row & 7) << 4);
            gload16(Ab + ((size_t)(bm + row) * Kld + kk) * 2 + kbs, (char*)lA[buf] + p);
        }
#pragma unroll
        for (int c = 0; c < BCH; c++) {
            int p = (c * NT + tid) * 16;
            int row = p >> 7, kb = p & 127;
            int kbs = kb ^ ((row & 7) << 4);
            gload16(Bb + ((size_t)(bn + row) * Kld + kk) * 2 + kbs, (char*)lB[buf] + p);
        }
    };

    f32x4 acc[FM][FN] = {};

    stage(0, 0);
    __syncthreads();
    int cur = 0;
    for (int kk = 0; kk < K; kk += 64) {
        if (kk + 64 < K) stage(cur ^ 1, kk + 64);
        const char* lAb = (const char*)lA[cur];
        const char* lBb = (const char*)lB[cur];
#pragma unroll
        for (int ks = 0; ks < 2; ks++) {
            short8 af[FM], bf[FN];
#pragma unroll
            for (int i = 0; i < FM; i++) {
                int row = wr * WM + i * 16 + lr;
                int kb = ks * 64 + lg * 16;
                af[i] = *(const short8*)(lAb + row * 128 + (kb ^ ((row & 7) << 4)));
            }
#pragma unroll
            for (int j = 0; j < FN; j++) {
                int row = wc * WN + j * 16 + lr;
                int kb = ks * 64 + lg * 16;
                bf[j] = *(const short8*)(lBb + row * 128 + (kb ^ ((row & 7) << 4)));
            }
#pragma unroll
            for (int i = 0; i < FM; i++)
#pragma unroll
                for (int j = 0; j < FN; j++)
                    acc[i][j] = __builtin_amdgcn_mfma_f32_16x16x32_bf16(af[i], bf[j], acc[i][j], 0, 0, 0);
        }
        __syncthreads();
        cur ^= 1;
    }

#pragma unroll
    for (int i = 0; i < FM; i++)
#pragma unroll
        for (int j = 0; j < FN; j++)
#pragma unroll
            for (int r = 0; r < 4; r++) {
                int gm = bm + wr * WM + i * 16 + lg * 4 + r;
                int gn = bn + wc * WN + j * 16 + lr;
                if (MODE == 3) {
                    cpb[(size_t)gm * DM + gn] = f2bf(acc[i][j][r]);
                    continue;
                }
                float v = acc[i][j][r] + bias[gn];
                if (MODE == 0) {
                    int bi = gm >> 10, tok = gm & (SEQ - 1);
                    int which = gn / DM;
                    int wi = gn - which * DM;
                    int h = wi >> 6, d = wi & 63;
                    if (which == 0)      o0[(((size_t)bi * NHD + h) * SEQ + tok) * HS + d] = f2bf(v * 0.125f);
                    else if (which == 1) o1[(((size_t)bi * NHD + h) * SEQ + tok) * HS + d] = f2bf(v);
                    else                 o2[(((size_t)bi * NHD + h) * HS + d) * SEQ + tok] = f2bf(v);
                } else if (MODE == 1) {
                    size_t ix = (size_t)gm * DM + gn;
                    xres[ix] += v;
                } else {
                    float g = 0.5f * v * (1.0f + erff(v * 0.70710678f));
                    o0[(size_t)gm * HID + gn] = f2bf(g);
                }
            }
}

// ---------------- flash attention, split-KV x2, XCD-swizzled (bh-major) --------
// Writes bf16 unnormalized O + fp32 (m,l) partials.
__global__ __launch_bounds__(256) void attn_k(
        const u16* __restrict__ q, const u16* __restrict__ k,
        const u16* __restrict__ vtg, u16* __restrict__ Of,
        float* __restrict__ ml) {
    __shared__ u16 kt[2][64 * 64];
    __shared__ u16 vtile[2][64 * 64];
    __shared__ u16 plds[4][16][72];

    int tid = threadIdx.x;
    int l = tid & 63, w = tid >> 6;
    int lr = l & 15, lg = l >> 4;

    int flat = (blockIdx.z * gridDim.y + blockIdx.y) * gridDim.x + blockIdx.x;
    int virt = (flat & 7) * 96 + (flat >> 3);
    int bh = virt >> 5;
    int rem = virt & 31;
    int half = rem >> 4;
    int qb = rem & 15;

    int qbase = qb * 64 + w * 16;
    int kv0 = half * (SEQ / 2);

    const u16* qp = q + (size_t)bh * SEQ * HS;
    const char* kp = (const char*)(k + (size_t)bh * SEQ * HS);
    const char* vp = (const char*)(vtg + (size_t)bh * HS * SEQ);

    short8 aq[2];
#pragma unroll
    for (int c = 0; c < 2; c++)
        aq[c] = *(const short8*)(qp + (size_t)(qbase + lr) * HS + c * 32 + lg * 8);

    auto stage = [&](int buf, int kb) {
#pragma unroll
        for (int c = 0; c < 2; c++) {
            int p = (c * 256 + tid) * 16;
            int row = p >> 7, db = p & 127;
            int dbs = db ^ ((row & 7) << 4);
            gload16(kp + (size_t)(kb + row) * 128 + dbs, (char*)kt[buf] + p);
        }
#pragma unroll
        for (int c = 0; c < 2; c++) {
            int p = (c * 256 + tid) * 16;
            int row = p >> 7, db = p & 127;
            int dbs = db ^ ((row & 7) << 4);
            gload16(vp + (size_t)row * (SEQ * 2) + kb * 2 + dbs, (char*)vtile[buf] + p);
        }
    };

    float mrow[4], lsum[4];
#pragma unroll
    for (int r = 0; r < 4; r++) { mrow[r] = -1e30f; lsum[r] = 0.f; }
    f32x4 oacc[4] = {};

    stage(0, kv0);
    __syncthreads();
    int buf = 0;
    for (int kb = kv0; kb < kv0 + SEQ / 2; kb += 64) {
        if (kb + 64 < kv0 + SEQ / 2) stage(buf ^ 1, kb + 64);
        const char* kb_ = (const char*)kt[buf];
        const char* vb_ = (const char*)vtile[buf];

        f32x4 s[4];
        __builtin_amdgcn_s_setprio(1);
#pragma unroll
        for (int t = 0; t < 4; t++) {
            f32x4 st = {};
#pragma unroll
            for (int c = 0; c < 2; c++) {
                int row = t * 16 + lr;
                short8 bk = *(const short8*)(kb_ + row * 128 + ((c * 64 + lg * 16) ^ ((row & 7) << 4)));
                st = __builtin_amdgcn_mfma_f32_16x16x32_bf16(aq[c], bk, st, 0, 0, 0);
            }
            s[t] = st;
        }
        __builtin_amdgcn_s_setprio(0);

        float e[4][4], scl[4];
#pragma unroll
        for (int r = 0; r < 4; r++) {
            float mx = fmaxf(fmaxf(s[0][r], s[1][r]), fmaxf(s[2][r], s[3][r]));
#pragma unroll
            for (int off = 8; off; off >>= 1) mx = fmaxf(mx, __shfl_xor(mx, off, 16));
            float mnew = fmaxf(mrow[r], mx);
            float sc = __expf(mrow[r] - mnew);
            float ss = 0.f;
#pragma unroll
            for (int t = 0; t < 4; t++) { e[t][r] = __expf(s[t][r] - mnew); ss += e[t][r]; }
#pragma unroll
            for (int off = 8; off; off >>= 1) ss += __shfl_xor(ss, off, 16);
            lsum[r] = lsum[r] * sc + ss;
            mrow[r] = mnew;
            scl[r] = sc;
        }
#pragma unroll
        for (int j = 0; j < 4; j++)
#pragma unroll
            for (int r = 0; r < 4; r++) oacc[j][r] *= scl[r];

#pragma unroll
        for (int t = 0; t < 4; t++)
#pragma unroll
            for (int r = 0; r < 4; r++)
                plds[w][lg * 4 + r][t * 16 + lr] = f2bf(e[t][r]);
        short8 pa[2];
#pragma unroll
        for (int kc = 0; kc < 2; kc++)
            pa[kc] = *(const short8*)(&plds[w][lr][kc * 32 + lg * 8]);

        __builtin_amdgcn_s_setprio(1);
#pragma unroll
        for (int j = 0; j < 4; j++) {
            int row = j * 16 + lr;
#pragma unroll
            for (int kc = 0; kc < 2; kc++) {
                short8 bv = *(const short8*)(vb_ + row * 128 + ((kc * 64 + lg * 16) ^ ((row & 7) << 4)));
                oacc[j] = __builtin_amdgcn_mfma_f32_16x16x32_bf16(pa[kc], bv, oacc[j], 0, 0, 0);
            }
        }
        __builtin_amdgcn_s_setprio(0);
        __syncthreads();
        buf ^= 1;
    }

    size_t pbase = ((size_t)(bh * 2 + half) * SEQ);
#pragma unroll
    for (int j = 0; j < 4; j++)
#pragma unroll
        for (int r = 0; r < 4; r++) {
            int qrow = qbase + lg * 4 + r;
            Of[(pbase + qrow) * 64 + j * 16 + lr] = f2bf(oacc[j][r]);
        }
    if (lr == 0) {
#pragma unroll
        for (int r = 0; r < 4; r++) {
            int qrow = qbase + lg * 4 + r;
            ((float2*)ml)[pbase + qrow] = make_float2(mrow[r], lsum[r]);
        }
    }
}

// ---------------- combine two KV halves (bf16 partials, fp32 math) -------------
__global__ __launch_bounds__(256) void attncomb_k(
        const u16* __restrict__ Of, const float* __restrict__ ml,
        u16* __restrict__ o) {
    int gid = blockIdx.x * 256 + threadIdx.x;
    int row = gid >> 4;
    int dc = (gid & 15) * 4;
    int bh = row >> 10, qrow = row & 1023;
    int bi = bh / NHD, h = bh - bi * NHD;
    const float2* mlp = (const float2*)ml;
    float2 ml0 = mlp[(size_t)(bh * 2 + 0) * SEQ + qrow];
    float2 ml1 = mlp[(size_t)(bh * 2 + 1) * SEQ + qrow];
    float m = fmaxf(ml0.x, ml1.x);
    float e0 = __expf(ml0.x - m), e1 = __expf(ml1.x - m);
    float rl = 1.0f / (ml0.y * e0 + ml1.y * e1);
    us4 o0 = *(const us4*)(Of + ((size_t)(bh * 2 + 0) * SEQ + qrow) * 64 + dc);
    us4 o1 = *(const us4*)(Of + ((size_t)(bh * 2 + 1) * SEQ + qrow) * 64 + dc);
    us4 u;
    u[0] = f2bf((bf2f(o0[0]) * e0 + bf2f(o1[0]) * e1) * rl);
    u[1] = f2bf((bf2f(o0[1]) * e0 + bf2f(o1[1]) * e1) * rl);
    u[2] = f2bf((bf2f(o0[2]) * e0 + bf2f(o1[2]) * e1) * rl);
    u[3] = f2bf((bf2f(o0[3]) * e0 + bf2f(o1[3]) * e1) * rl);
    *(us4*)(o + ((size_t)(bi * SEQ + qrow) * DM) + h * HS + dc) = u;
}

// ---------------- host ----------------
extern "C" void kernel_launch(void* const* d_in, const int* in_sizes, int n_in,
                              void* d_out, int out_size, void* d_ws, size_t ws_size,
                              hipStream_t stream) {
    const float* x_in  = (const float*)d_in[0];
    const float* Wqkv  = (const float*)d_in[1];
    const float* bqkv  = (const float*)d_in[2];
    const float* Wproj = (const float*)d_in[3];
    const float* bproj = (const float*)d_in[4];
    const float* W1    = (const float*)d_in[5];
    const float* b1    = (const float*)d_in[6];
    const float* W2    = (const float*)d_in[7];
    const float* b2    = (const float*)d_in[8];
    const float* ln1w  = (const float*)d_in[9];
    const float* ln1b  = (const float*)d_in[10];
    const float* ln2w  = (const float*)d_in[11];
    const float* ln2b  = (const float*)d_in[12];
    const float* lnw   = (const float*)d_in[13];
    const float* lnb   = (const float*)d_in[14];

    char* ws = (char*)d_ws;
    size_t off = 0;
    auto alloc = [&](size_t bytes) -> void* {
        void* p = ws + off;
        off += (bytes + 255) & ~(size_t)255;
        return p;
    };
    float* xbuf = (float*)alloc((size_t)NTOK * DM * 4);
    u16* hbuf   = (u16*)alloc((size_t)NTOK * DM * 2);
    u16* qb     = (u16*)alloc((size_t)2 * NHD * SEQ * HS * 2);
    u16* kb     = (u16*)alloc((size_t)2 * NHD * SEQ * HS * 2);
    u16* vtb    = (u16*)alloc((size_t)2 * NHD * SEQ * HS * 2);
    u16* ob     = (u16*)alloc((size_t)NTOK * DM * 2);
    u16* h2b    = (u16*)alloc((size_t)NTOK * HID * 2);
    u16* Of     = (u16*)alloc((size_t)24 * 2 * SEQ * 64 * 2);
    float* mlb  = (float*)alloc((size_t)24 * 2 * SEQ * 8);
    u16* skbuf  = (u16*)alloc((size_t)4 * NTOK * DM * 2);

    const size_t nWqkv  = (size_t)NL * 3 * DM * DM;
    const size_t nWproj = (size_t)NL * DM * DM;
    const size_t nW1    = (size_t)NL * HID * DM;
    const size_t nW2    = (size_t)NL * DM * HID;
    size_t wbytes = (nWqkv + nWproj + nW1 + nW2) * 2 + 4 * 256;
    bool wb = (off + wbytes) <= ws_size;

    u16 *wqkvh = nullptr, *wprojh = nullptr, *w1h = nullptr, *w2h = nullptr;
    u16 *cvtbuf = nullptr;
    if (wb) {
        wqkvh  = (u16*)alloc(nWqkv * 2);
        wprojh = (u16*)alloc(nWproj * 2);
        w1h    = (u16*)alloc(nW1 * 2);
        w2h    = (u16*)alloc(nW2 * 2);
    } else {
        cvtbuf = (u16*)alloc((size_t)HID * DM * 2);
    }

    if (wb) {
        unsigned nb0 = (unsigned)(nWqkv / 2048);   // 2048-float tiles
        unsigned nb1 = (unsigned)(nWproj / 2048);
        unsigned nb2 = (unsigned)(nW1 / 2048);
        unsigned nb3 = (unsigned)(nW2 / 2048);
        cvt4_k<<<dim3(nb0 + nb1 + nb2 + nb3), 256, 0, stream>>>(
            Wqkv, wqkvh, nb0, Wproj, wprojh, nb1, W1, w1h, nb2, W2, w2h);
    }
    // fused posadd + LN1(layer 0)
    posln_k<<<dim3(NTOK / 4), 256, 0, stream>>>(x_in, xbuf, ln1w, ln1b, hbuf);

    for (int l = 0; l < NL; l++) {
        const u16* wqkv_l;
        const u16* wproj_l;
        const u16* w1_l;
        const u16* w2_l;

        if (wb) wqkv_l = wqkvh + (size_t)l * 3 * DM * DM;
        else {
            cvt_k<<<dim3(3 * DM * DM / 1024), 256, 0, stream>>>(Wqkv + (size_t)l * 3 * DM * DM, cvtbuf);
            wqkv_l = cvtbuf;
        }
        gemm_k<128, 64, 256, 2, 2, 0><<<dim3(3 * DM / 64, NTOK / 128), 256, 0, stream>>>(
            hbuf, wqkv_l, bqkv + (size_t)l * 3 * DM, DM, DM,
            nullptr, qb, kb, vtb, nullptr);

        attn_k<<<dim3(SEQ / 64, 24, 2), 256, 0, stream>>>(qb, kb, vtb, Of, mlb);
        attncomb_k<<<dim3(24 * SEQ * 16 / 256), 256, 0, stream>>>(Of, mlb, ob);

        if (wb) wproj_l = wprojh + (size_t)l * DM * DM;
        else {
            cvt_k<<<dim3(DM * DM / 1024), 256, 0, stream>>>(Wproj + (size_t)l * DM * DM, cvtbuf);
            wproj_l = cvtbuf;
        }
        // proj: split-K x2 -> skbuf (bf16); fused reduce+residual+LN2 -> hbuf
        gemm_k<64, 64, 256, 2, 2, 3><<<dim3(DM / 64, NTOK / 64, 2), 256, 0, stream>>>(
            ob, wproj_l, nullptr, DM / 2, DM,
            nullptr, nullptr, nullptr, nullptr, skbuf);
        skredln_k<2, true><<<dim3(NTOK / 4), 256, 0, stream>>>(
            skbuf, bproj + (size_t)l * DM, xbuf,
            ln2w + (size_t)l * DM, ln2b + (size_t)l * DM, hbuf);

        if (wb) w1_l = w1h + (size_t)l * HID * DM;
        else {
            cvt_k<<<dim3(HID * DM / 1024), 256, 0, stream>>>(W1 + (size_t)l * HID * DM, cvtbuf);
            w1_l = cvtbuf;
        }
        gemm_k<128, 64, 256, 2, 2, 2><<<dim3(HID / 64, NTOK / 128), 256, 0, stream>>>(
            hbuf, w1_l, b1 + (size_t)l * HID, DM, DM,
            nullptr, h2b, nullptr, nullptr, nullptr);

        if (wb) w2_l = w2h + (size_t)l * DM * HID;
        else {
            cvt_k<<<dim3(DM * HID / 1024), 256, 0, stream>>>(W2 + (size_t)l * DM * HID, cvtbuf);
            w2_l = cvtbuf;
        }
        // fc2: split-K x4 -> skbuf (bf16); fused reduce+residual+(next LN1 or
        // final LN -> d_out)
        gemm_k<64, 64, 256, 2, 2, 3><<<dim3(DM / 64, NTOK / 64, 4), 256, 0, stream>>>(
            h2b, w2_l, nullptr, HID / 4, HID,
            nullptr, nullptr, nullptr, nullptr, skbuf);
        if (l + 1 < NL) {
            skredln_k<4, true><<<dim3(NTOK / 4), 256, 0, stream>>>(
                skbuf, b2 + (size_t)l * DM, xbuf,
                ln1w + (size_t)(l + 1) * DM, ln1b + (size_t)(l + 1) * DM, hbuf);
        } else {
            skredln_k<4, false><<<dim3(NTOK / 4), 256, 0, stream>>>(
                skbuf, b2 + (size_t)l * DM, xbuf, lnw, lnb, (float*)d_out);
        }
    }
}

// Round 22
// 1529.517 us; speedup vs baseline: 1.0388x; 1.0388x over previous
//
#include <hip/hip_runtime.h>
#include <math.h>

#define NTOK 2048
#define DM 768
#define NHD 12
#define HS 64
#define SEQ 1024
#define HID 3072
#define NL 12

typedef __attribute__((ext_vector_type(8))) short short8;
typedef __attribute__((ext_vector_type(4))) float f32x4;
typedef __attribute__((ext_vector_type(4))) unsigned short us4;
typedef unsigned short u16;

static __device__ __forceinline__ u16 f2bf(float f) {
    unsigned u = __float_as_uint(f);
    u = (u + 0x7fffu + ((u >> 16) & 1u)) >> 16;
    return (u16)u;
}
static __device__ __forceinline__ float bf2f(u16 v) {
    return __uint_as_float(((unsigned)v) << 16);
}

static __device__ __forceinline__ void gload16(const void* g, void* l) {
    __builtin_amdgcn_global_load_lds(
        (const __attribute__((address_space(1))) void*)g,
        (__attribute__((address_space(3))) void*)l,
        16, 0, 0);
}

// ---------------- fused x + sincos pos embed + LN1(layer0): 1 wave per row -----
__global__ __launch_bounds__(256) void posln_k(
        const float* __restrict__ xin, float* __restrict__ xbuf,
        const float* __restrict__ w, const float* __restrict__ b,
        u16* __restrict__ hbuf) {
    int l = threadIdx.x & 63, wv = threadIdx.x >> 6;
    int row = blockIdx.x * 4 + wv;
    int tok = row & (SEQ - 1);
    size_t ro = (size_t)row * DM;
    float4 v[3];
#pragma unroll
    for (int c = 0; c < 3; c++) {
        int col = c * 256 + l * 4;
        float4 x4 = *(const float4*)(xin + ro + col);
        float pe[4];
#pragma unroll
        for (int j = 0; j < 4; j++) {
            int d = col + j;
            int i = (d < 384) ? d : d - 384;
            float omega = expf((float)i * (-9.210340371976184f / 384.0f));
            float ang = (float)tok * omega;
            pe[j] = (d < 384) ? sinf(ang) : cosf(ang);
        }
        x4.x += pe[0]; x4.y += pe[1]; x4.z += pe[2]; x4.w += pe[3];
        *(float4*)(xbuf + ro + col) = x4;
        v[c] = x4;
    }
    float s = 0.f;
#pragma unroll
    for (int c = 0; c < 3; c++) s += v[c].x + v[c].y + v[c].z + v[c].w;
#pragma unroll
    for (int off = 32; off; off >>= 1) s += __shfl_xor(s, off, 64);
    float mu = s * (1.0f / DM);
    float vs = 0.f;
#pragma unroll
    for (int c = 0; c < 3; c++) {
        float dx;
        dx = v[c].x - mu; vs += dx * dx;
        dx = v[c].y - mu; vs += dx * dx;
        dx = v[c].z - mu; vs += dx * dx;
        dx = v[c].w - mu; vs += dx * dx;
    }
#pragma unroll
    for (int off = 32; off; off >>= 1) vs += __shfl_xor(vs, off, 64);
    float rstd = rsqrtf(vs * (1.0f / DM) + 1e-5f);
#pragma unroll
    for (int c = 0; c < 3; c++) {
        int col = c * 256 + l * 4;
        float4 w4 = *(const float4*)(w + col);
        float4 b4 = *(const float4*)(b + col);
        us4 u = { f2bf((v[c].x - mu) * rstd * w4.x + b4.x),
                  f2bf((v[c].y - mu) * rstd * w4.y + b4.y),
                  f2bf((v[c].z - mu) * rstd * w4.z + b4.z),
                  f2bf((v[c].w - mu) * rstd * w4.w + b4.w) };
        *(us4*)(hbuf + ro + col) = u;
    }
}

// ---------------- fp32 -> bf16, 4 tensors in one launch (R18 best form) --------
__global__ void cvt4_k(const float* __restrict__ s0, u16* __restrict__ d0, unsigned n0,
                       const float* __restrict__ s1, u16* __restrict__ d1, unsigned n1,
                       const float* __restrict__ s2, u16* __restrict__ d2, unsigned n2,
                       const float* __restrict__ s3, u16* __restrict__ d3) {
    unsigned i = blockIdx.x * 256 + threadIdx.x;
    const float* s; u16* d;
    if (i < n0) { s = s0; d = d0; }
    else { i -= n0;
        if (i < n1) { s = s1; d = d1; }
        else { i -= n1;
            if (i < n2) { s = s2; d = d2; }
            else { i -= n2; s = s3; d = d3; }
        }
    }
    float4 f = ((const float4*)s)[i];
    us4 u = { f2bf(f.x), f2bf(f.y), f2bf(f.z), f2bf(f.w) };
    ((us4*)d)[i] = u;
}

// ---------------- fp32 -> bf16 (x4), single tensor (fallback path) -------------
__global__ void cvt_k(const float* __restrict__ in, u16* __restrict__ out) {
    int idx = blockIdx.x * 256 + threadIdx.x;
    float4 f = ((const float4*)in)[idx];
    us4 u = { f2bf(f.x), f2bf(f.y), f2bf(f.z), f2bf(f.w) };
    ((us4*)out)[idx] = u;
}

// ---- fused split-K reduce + residual + LayerNorm: 1 wave per row --------------
// Partials are bf16; accumulate fp32 in fixed order (deterministic).
template<int SK, bool OUTBF>
__global__ __launch_bounds__(256) void skredln_k(
        const u16* __restrict__ cp, const float* __restrict__ bias,
        float* __restrict__ xres, const float* __restrict__ w,
        const float* __restrict__ b, void* __restrict__ out) {
    int l = threadIdx.x & 63, wv = threadIdx.x >> 6;
    int row = blockIdx.x * 4 + wv;
    size_t ro = (size_t)row * DM;
    float4 v[3];
#pragma unroll
    for (int c = 0; c < 3; c++) {
        int col = c * 256 + l * 4;
        float4 s = *(const float4*)(bias + col);
#pragma unroll
        for (int p = 0; p < SK; p++) {
            us4 pv = *(const us4*)(cp + (size_t)p * (NTOK * DM) + ro + col);
            s.x += bf2f(pv[0]); s.y += bf2f(pv[1]);
            s.z += bf2f(pv[2]); s.w += bf2f(pv[3]);
        }
        float4 x4 = *(const float4*)(xres + ro + col);
        x4.x += s.x; x4.y += s.y; x4.z += s.z; x4.w += s.w;
        *(float4*)(xres + ro + col) = x4;
        v[c] = x4;
    }
    float s = 0.f;
#pragma unroll
    for (int c = 0; c < 3; c++) s += v[c].x + v[c].y + v[c].z + v[c].w;
#pragma unroll
    for (int off = 32; off; off >>= 1) s += __shfl_xor(s, off, 64);
    float mu = s * (1.0f / DM);
    float vs = 0.f;
#pragma unroll
    for (int c = 0; c < 3; c++) {
        float dx;
        dx = v[c].x - mu; vs += dx * dx;
        dx = v[c].y - mu; vs += dx * dx;
        dx = v[c].z - mu; vs += dx * dx;
        dx = v[c].w - mu; vs += dx * dx;
    }
#pragma unroll
    for (int off = 32; off; off >>= 1) vs += __shfl_xor(vs, off, 64);
    float rstd = rsqrtf(vs * (1.0f / DM) + 1e-5f);
#pragma unroll
    for (int c = 0; c < 3; c++) {
        int col = c * 256 + l * 4;
        float4 w4 = *(const float4*)(w + col);
        float4 b4 = *(const float4*)(b + col);
        float y0 = (v[c].x - mu) * rstd * w4.x + b4.x;
        float y1 = (v[c].y - mu) * rstd * w4.y + b4.y;
        float y2 = (v[c].z - mu) * rstd * w4.z + b4.z;
        float y3 = (v[c].w - mu) * rstd * w4.w + b4.w;
        if (OUTBF) {
            us4 u = { f2bf(y0), f2bf(y1), f2bf(y2), f2bf(y3) };
            *(us4*)((u16*)out + ro + col) = u;
        } else {
            float4 o4 = { y0, y1, y2, y3 };
            *(float4*)((float*)out + ro + col) = o4;
        }
    }
}

// ---------------- LDS-staged GEMM, double-buffered, XCD-swizzled ---------------
// MODE 0: qkv scatter  1: residual add  2: GELU (ld HID)  3: split-K bf16 partial
template<int BM, int BN, int NT, int WR, int WC, int MODE>
__global__ __launch_bounds__(NT) void gemm_k(
        const u16* __restrict__ A, const u16* __restrict__ B,
        const float* __restrict__ bias, int K, int Kld,
        float* __restrict__ xres, u16* __restrict__ o0, u16* __restrict__ o1,
        u16* __restrict__ o2, u16* __restrict__ cp) {
    constexpr int WM = BM / WR, WN = BN / WC;
    constexpr int FM = WM / 16, FN = WN / 16;
    constexpr int ACH = (BM * 128) / (NT * 16);
    constexpr int BCH = (BN * 128) / (NT * 16);

    __shared__ u16 lA[2][BM * 64];
    __shared__ u16 lB[2][BN * 64];

    int tid = threadIdx.x;
    int l = tid & 63, w = tid >> 6;
    int lr = l & 15, lg = l >> 4;
    int wr = w / WC, wc = w % WC;

    int gx = gridDim.x, gy = gridDim.y;
    int nwg = gx * gy;
    int flat = blockIdx.y * gx + blockIdx.x;
    int virt = (flat & 7) * (nwg >> 3) + (flat >> 3);
    int bx = virt / gy;
    int by = virt % gy;
    int bm = by * BM;
    int bn = bx * BN;

    int koff = (MODE == 3) ? blockIdx.z * K : 0;
    const char* Ab = (const char*)A + (size_t)koff * 2;
    const char* Bb = (const char*)B + (size_t)koff * 2;
    u16* cpb = (MODE == 3) ? cp + (size_t)blockIdx.z * NTOK * DM : nullptr;

    auto stage = [&](int buf, int kk) {
#pragma unroll
        for (int c = 0; c < ACH; c++) {
            int p = (c * NT + tid) * 16;
            int row = p >> 7, kb = p & 127;
            int kbs = kb ^ ((row & 7) << 4);
            gload16(Ab + ((size_t)(bm + row) * Kld + kk) * 2 + kbs, (char*)lA[buf] + p);
        }
#pragma unroll
        for (int c = 0; c < BCH; c++) {
            int p = (c * NT + tid) * 16;
            int row = p >> 7, kb = p & 127;
            int kbs = kb ^ ((row & 7) << 4);
            gload16(Bb + ((size_t)(bn + row) * Kld + kk) * 2 + kbs, (char*)lB[buf] + p);
        }
    };

    f32x4 acc[FM][FN] = {};

    stage(0, 0);
    __syncthreads();
    int cur = 0;
    for (int kk = 0; kk < K; kk += 64) {
        if (kk + 64 < K) stage(cur ^ 1, kk + 64);
        const char* lAb = (const char*)lA[cur];
        const char* lBb = (const char*)lB[cur];
#pragma unroll
        for (int ks = 0; ks < 2; ks++) {
            short8 af[FM], bf[FN];
#pragma unroll
            for (int i = 0; i < FM; i++) {
                int row = wr * WM + i * 16 + lr;
                int kb = ks * 64 + lg * 16;
                af[i] = *(const short8*)(lAb + row * 128 + (kb ^ ((row & 7) << 4)));
            }
#pragma unroll
            for (int j = 0; j < FN; j++) {
                int row = wc * WN + j * 16 + lr;
                int kb = ks * 64 + lg * 16;
                bf[j] = *(const short8*)(lBb + row * 128 + (kb ^ ((row & 7) << 4)));
            }
#pragma unroll
            for (int i = 0; i < FM; i++)
#pragma unroll
                for (int j = 0; j < FN; j++)
                    acc[i][j] = __builtin_amdgcn_mfma_f32_16x16x32_bf16(af[i], bf[j], acc[i][j], 0, 0, 0);
        }
        __syncthreads();
        cur ^= 1;
    }

#pragma unroll
    for (int i = 0; i < FM; i++)
#pragma unroll
        for (int j = 0; j < FN; j++)
#pragma unroll
            for (int r = 0; r < 4; r++) {
                int gm = bm + wr * WM + i * 16 + lg * 4 + r;
                int gn = bn + wc * WN + j * 16 + lr;
                if (MODE == 3) {
                    cpb[(size_t)gm * DM + gn] = f2bf(acc[i][j][r]);
                    continue;
                }
                float v = acc[i][j][r] + bias[gn];
                if (MODE == 0) {
                    int bi = gm >> 10, tok = gm & (SEQ - 1);
                    int which = gn / DM;
                    int wi = gn - which * DM;
                    int h = wi >> 6, d = wi & 63;
                    if (which == 0)      o0[(((size_t)bi * NHD + h) * SEQ + tok) * HS + d] = f2bf(v * 0.125f);
                    else if (which == 1) o1[(((size_t)bi * NHD + h) * SEQ + tok) * HS + d] = f2bf(v);
                    else                 o2[(((size_t)bi * NHD + h) * HS + d) * SEQ + tok] = f2bf(v);
                } else if (MODE == 1) {
                    size_t ix = (size_t)gm * DM + gn;
                    xres[ix] += v;
                } else {
                    float g = 0.5f * v * (1.0f + erff(v * 0.70710678f));
                    o0[(size_t)gm * HID + gn] = f2bf(g);
                }
            }
}

// ---------------- flash attention, split-KV x2, XCD-swizzled (bh-major) --------
// Writes bf16 unnormalized O + fp32 (m,l) partials.
__global__ __launch_bounds__(256) void attn_k(
        const u16* __restrict__ q, const u16* __restrict__ k,
        const u16* __restrict__ vtg, u16* __restrict__ Of,
        float* __restrict__ ml) {
    __shared__ u16 kt[2][64 * 64];
    __shared__ u16 vtile[2][64 * 64];
    __shared__ u16 plds[4][16][72];

    int tid = threadIdx.x;
    int l = tid & 63, w = tid >> 6;
    int lr = l & 15, lg = l >> 4;

    int flat = (blockIdx.z * gridDim.y + blockIdx.y) * gridDim.x + blockIdx.x;
    int virt = (flat & 7) * 96 + (flat >> 3);
    int bh = virt >> 5;
    int rem = virt & 31;
    int half = rem >> 4;
    int qb = rem & 15;

    int qbase = qb * 64 + w * 16;
    int kv0 = half * (SEQ / 2);

    const u16* qp = q + (size_t)bh * SEQ * HS;
    const char* kp = (const char*)(k + (size_t)bh * SEQ * HS);
    const char* vp = (const char*)(vtg + (size_t)bh * HS * SEQ);

    short8 aq[2];
#pragma unroll
    for (int c = 0; c < 2; c++)
        aq[c] = *(const short8*)(qp + (size_t)(qbase + lr) * HS + c * 32 + lg * 8);

    auto stage = [&](int buf, int kb) {
#pragma unroll
        for (int c = 0; c < 2; c++) {
            int p = (c * 256 + tid) * 16;
            int row = p >> 7, db = p & 127;
            int dbs = db ^ ((row & 7) << 4);
            gload16(kp + (size_t)(kb + row) * 128 + dbs, (char*)kt[buf] + p);
        }
#pragma unroll
        for (int c = 0; c < 2; c++) {
            int p = (c * 256 + tid) * 16;
            int row = p >> 7, db = p & 127;
            int dbs = db ^ ((row & 7) << 4);
            gload16(vp + (size_t)row * (SEQ * 2) + kb * 2 + dbs, (char*)vtile[buf] + p);
        }
    };

    float mrow[4], lsum[4];
#pragma unroll
    for (int r = 0; r < 4; r++) { mrow[r] = -1e30f; lsum[r] = 0.f; }
    f32x4 oacc[4] = {};

    stage(0, kv0);
    __syncthreads();
    int buf = 0;
    for (int kb = kv0; kb < kv0 + SEQ / 2; kb += 64) {
        if (kb + 64 < kv0 + SEQ / 2) stage(buf ^ 1, kb + 64);
        const char* kb_ = (const char*)kt[buf];
        const char* vb_ = (const char*)vtile[buf];

        f32x4 s[4];
        __builtin_amdgcn_s_setprio(1);
#pragma unroll
        for (int t = 0; t < 4; t++) {
            f32x4 st = {};
#pragma unroll
            for (int c = 0; c < 2; c++) {
                int row = t * 16 + lr;
                short8 bk = *(const short8*)(kb_ + row * 128 + ((c * 64 + lg * 16) ^ ((row & 7) << 4)));
                st = __builtin_amdgcn_mfma_f32_16x16x32_bf16(aq[c], bk, st, 0, 0, 0);
            }
            s[t] = st;
        }
        __builtin_amdgcn_s_setprio(0);

        float e[4][4], scl[4];
#pragma unroll
        for (int r = 0; r < 4; r++) {
            float mx = fmaxf(fmaxf(s[0][r], s[1][r]), fmaxf(s[2][r], s[3][r]));
#pragma unroll
            for (int off = 8; off; off >>= 1) mx = fmaxf(mx, __shfl_xor(mx, off, 16));
            float mnew = fmaxf(mrow[r], mx);
            float sc = __expf(mrow[r] - mnew);
            float ss = 0.f;
#pragma unroll
            for (int t = 0; t < 4; t++) { e[t][r] = __expf(s[t][r] - mnew); ss += e[t][r]; }
#pragma unroll
            for (int off = 8; off; off >>= 1) ss += __shfl_xor(ss, off, 16);
            lsum[r] = lsum[r] * sc + ss;
            mrow[r] = mnew;
            scl[r] = sc;
        }
#pragma unroll
        for (int j = 0; j < 4; j++)
#pragma unroll
            for (int r = 0; r < 4; r++) oacc[j][r] *= scl[r];

#pragma unroll
        for (int t = 0; t < 4; t++)
#pragma unroll
            for (int r = 0; r < 4; r++)
                plds[w][lg * 4 + r][t * 16 + lr] = f2bf(e[t][r]);
        short8 pa[2];
#pragma unroll
        for (int kc = 0; kc < 2; kc++)
            pa[kc] = *(const short8*)(&plds[w][lr][kc * 32 + lg * 8]);

        __builtin_amdgcn_s_setprio(1);
#pragma unroll
        for (int j = 0; j < 4; j++) {
            int row = j * 16 + lr;
#pragma unroll
            for (int kc = 0; kc < 2; kc++) {
                short8 bv = *(const short8*)(vb_ + row * 128 + ((kc * 64 + lg * 16) ^ ((row & 7) << 4)));
                oacc[j] = __builtin_amdgcn_mfma_f32_16x16x32_bf16(pa[kc], bv, oacc[j], 0, 0, 0);
            }
        }
        __builtin_amdgcn_s_setprio(0);
        __syncthreads();
        buf ^= 1;
    }

    size_t pbase = ((size_t)(bh * 2 + half) * SEQ);
#pragma unroll
    for (int j = 0; j < 4; j++)
#pragma unroll
        for (int r = 0; r < 4; r++) {
            int qrow = qbase + lg * 4 + r;
            Of[(pbase + qrow) * 64 + j * 16 + lr] = f2bf(oacc[j][r]);
        }
    if (lr == 0) {
#pragma unroll
        for (int r = 0; r < 4; r++) {
            int qrow = qbase + lg * 4 + r;
            ((float2*)ml)[pbase + qrow] = make_float2(mrow[r], lsum[r]);
        }
    }
}

// ---------------- combine two KV halves (bf16 partials, fp32 math) -------------
__global__ __launch_bounds__(256) void attncomb_k(
        const u16* __restrict__ Of, const float* __restrict__ ml,
        u16* __restrict__ o) {
    int gid = blockIdx.x * 256 + threadIdx.x;
    int row = gid >> 4;
    int dc = (gid & 15) * 4;
    int bh = row >> 10, qrow = row & 1023;
    int bi = bh / NHD, h = bh - bi * NHD;
    const float2* mlp = (const float2*)ml;
    float2 ml0 = mlp[(size_t)(bh * 2 + 0) * SEQ + qrow];
    float2 ml1 = mlp[(size_t)(bh * 2 + 1) * SEQ + qrow];
    float m = fmaxf(ml0.x, ml1.x);
    float e0 = __expf(ml0.x - m), e1 = __expf(ml1.x - m);
    float rl = 1.0f / (ml0.y * e0 + ml1.y * e1);
    us4 o0 = *(const us4*)(Of + ((size_t)(bh * 2 + 0) * SEQ + qrow) * 64 + dc);
    us4 o1 = *(const us4*)(Of + ((size_t)(bh * 2 + 1) * SEQ + qrow) * 64 + dc);
    us4 u;
    u[0] = f2bf((bf2f(o0[0]) * e0 + bf2f(o1[0]) * e1) * rl);
    u[1] = f2bf((bf2f(o0[1]) * e0 + bf2f(o1[1]) * e1) * rl);
    u[2] = f2bf((bf2f(o0[2]) * e0 + bf2f(o1[2]) * e1) * rl);
    u[3] = f2bf((bf2f(o0[3]) * e0 + bf2f(o1[3]) * e1) * rl);
    *(us4*)(o + ((size_t)(bi * SEQ + qrow) * DM) + h * HS + dc) = u;
}

// ---------------- host ----------------
extern "C" void kernel_launch(void* const* d_in, const int* in_sizes, int n_in,
                              void* d_out, int out_size, void* d_ws, size_t ws_size,
                              hipStream_t stream) {
    const float* x_in  = (const float*)d_in[0];
    const float* Wqkv  = (const float*)d_in[1];
    const float* bqkv  = (const float*)d_in[2];
    const float* Wproj = (const float*)d_in[3];
    const float* bproj = (const float*)d_in[4];
    const float* W1    = (const float*)d_in[5];
    const float* b1    = (const float*)d_in[6];
    const float* W2    = (const float*)d_in[7];
    const float* b2    = (const float*)d_in[8];
    const float* ln1w  = (const float*)d_in[9];
    const float* ln1b  = (const float*)d_in[10];
    const float* ln2w  = (const float*)d_in[11];
    const float* ln2b  = (const float*)d_in[12];
    const float* lnw   = (const float*)d_in[13];
    const float* lnb   = (const float*)d_in[14];

    char* ws = (char*)d_ws;
    size_t off = 0;
    auto alloc = [&](size_t bytes) -> void* {
        void* p = ws + off;
        off += (bytes + 255) & ~(size_t)255;
        return p;
    };
    float* xbuf = (float*)alloc((size_t)NTOK * DM * 4);
    u16* hbuf   = (u16*)alloc((size_t)NTOK * DM * 2);
    u16* qb     = (u16*)alloc((size_t)2 * NHD * SEQ * HS * 2);
    u16* kb     = (u16*)alloc((size_t)2 * NHD * SEQ * HS * 2);
    u16* vtb    = (u16*)alloc((size_t)2 * NHD * SEQ * HS * 2);
    u16* ob     = (u16*)alloc((size_t)NTOK * DM * 2);
    u16* h2b    = (u16*)alloc((size_t)NTOK * HID * 2);
    u16* Of     = (u16*)alloc((size_t)24 * 2 * SEQ * 64 * 2);
    float* mlb  = (float*)alloc((size_t)24 * 2 * SEQ * 8);
    u16* skbuf  = (u16*)alloc((size_t)4 * NTOK * DM * 2);

    const size_t nWqkv  = (size_t)NL * 3 * DM * DM;
    const size_t nWproj = (size_t)NL * DM * DM;
    const size_t nW1    = (size_t)NL * HID * DM;
    const size_t nW2    = (size_t)NL * DM * HID;
    size_t wbytes = (nWqkv + nWproj + nW1 + nW2) * 2 + 4 * 256;
    bool wb = (off + wbytes) <= ws_size;

    u16 *wqkvh = nullptr, *wprojh = nullptr, *w1h = nullptr, *w2h = nullptr;
    u16 *cvtbuf = nullptr;
    if (wb) {
        wqkvh  = (u16*)alloc(nWqkv * 2);
        wprojh = (u16*)alloc(nWproj * 2);
        w1h    = (u16*)alloc(nW1 * 2);
        w2h    = (u16*)alloc(nW2 * 2);
    } else {
        cvtbuf = (u16*)alloc((size_t)HID * DM * 2);
    }

    if (wb) {
        unsigned n0 = (unsigned)(nWqkv / 4), n1 = (unsigned)(nWproj / 4);
        unsigned n2 = (unsigned)(nW1 / 4);
        unsigned ntot = n0 + n1 + n2 + (unsigned)(nW2 / 4);
        cvt4_k<<<dim3((ntot + 255) / 256), 256, 0, stream>>>(
            Wqkv, wqkvh, n0, Wproj, wprojh, n1, W1, w1h, n2, W2, w2h);
    }
    // fused posadd + LN1(layer 0)
    posln_k<<<dim3(NTOK / 4), 256, 0, stream>>>(x_in, xbuf, ln1w, ln1b, hbuf);

    for (int l = 0; l < NL; l++) {
        const u16* wqkv_l;
        const u16* wproj_l;
        const u16* w1_l;
        const u16* w2_l;

        if (wb) wqkv_l = wqkvh + (size_t)l * 3 * DM * DM;
        else {
            cvt_k<<<dim3(3 * DM * DM / 1024), 256, 0, stream>>>(Wqkv + (size_t)l * 3 * DM * DM, cvtbuf);
            wqkv_l = cvtbuf;
        }
        gemm_k<128, 64, 256, 2, 2, 0><<<dim3(3 * DM / 64, NTOK / 128), 256, 0, stream>>>(
            hbuf, wqkv_l, bqkv + (size_t)l * 3 * DM, DM, DM,
            nullptr, qb, kb, vtb, nullptr);

        attn_k<<<dim3(SEQ / 64, 24, 2), 256, 0, stream>>>(qb, kb, vtb, Of, mlb);
        attncomb_k<<<dim3(24 * SEQ * 16 / 256), 256, 0, stream>>>(Of, mlb, ob);

        if (wb) wproj_l = wprojh + (size_t)l * DM * DM;
        else {
            cvt_k<<<dim3(DM * DM / 1024), 256, 0, stream>>>(Wproj + (size_t)l * DM * DM, cvtbuf);
            wproj_l = cvtbuf;
        }
        // proj: split-K x2 -> skbuf (bf16); fused reduce+residual+LN2 -> hbuf
        gemm_k<64, 64, 256, 2, 2, 3><<<dim3(DM / 64, NTOK / 64, 2), 256, 0, stream>>>(
            ob, wproj_l, nullptr, DM / 2, DM,
            nullptr, nullptr, nullptr, nullptr, skbuf);
        skredln_k<2, true><<<dim3(NTOK / 4), 256, 0, stream>>>(
            skbuf, bproj + (size_t)l * DM, xbuf,
            ln2w + (size_t)l * DM, ln2b + (size_t)l * DM, hbuf);

        if (wb) w1_l = w1h + (size_t)l * HID * DM;
        else {
            cvt_k<<<dim3(HID * DM / 1024), 256, 0, stream>>>(W1 + (size_t)l * HID * DM, cvtbuf);
            w1_l = cvtbuf;
        }
        gemm_k<128, 64, 256, 2, 2, 2><<<dim3(HID / 64, NTOK / 128), 256, 0, stream>>>(
            hbuf, w1_l, b1 + (size_t)l * HID, DM, DM,
            nullptr, h2b, nullptr, nullptr, nullptr);

        if (wb) w2_l = w2h + (size_t)l * DM * HID;
        else {
            cvt_k<<<dim3(DM * HID / 1024), 256, 0, stream>>>(W2 + (size_t)l * DM * HID, cvtbuf);
            w2_l = cvtbuf;
        }
        // fc2: split-K x4 -> skbuf (bf16); fused reduce+residual+(next LN1 or
        // final LN -> d_out)
        gemm_k<64, 64, 256, 2, 2, 3><<<dim3(DM / 64, NTOK / 64, 4), 256, 0, stream>>>(
            h2b, w2_l, nullptr, HID / 4, HID,
            nullptr, nullptr, nullptr, nullptr, skbuf);
        if (l + 1 < NL) {
            skredln_k<4, true><<<dim3(NTOK / 4), 256, 0, stream>>>(
                skbuf, b2 + (size_t)l * DM, xbuf,
                ln1w + (size_t)(l + 1) * DM, ln1b + (size_t)(l + 1) * DM, hbuf);
        } else {
            skredln_k<4, false><<<dim3(NTOK / 4), 256, 0, stream>>>(
                skbuf, b2 + (size_t)l * DM, xbuf, lnw, lnb, (float*)d_out);
        }
    }
}